// Round 3
// baseline (190.444 us; speedup 1.0000x reference)
//
#include <hip/hip_runtime.h>

// DirectionalProcessor: out[b,y,x,o] = bc[o] + sum_{d,c} g[b,y-dy_d,x-dx_d,c] * M_d[c,o]
// with M_d[c,o] = sum_e Wd[d,c,e]*Wc[o,d*256+e]  (folded -> 68.7 GFLOP implicit GEMM
// [65536 x 2048] @ [2048 x 256], B,H,W,C=16,64,64,256, 8 dirs).
//
// R8: cut LDS traffic + break phase serialization. R7 (A+B both in LDS) had a
// ~1500 cy/iter LDS floor (96 KB reads + 48 KB writes) and, worse, all 8 waves
// were barrier-locked into read-phase-then-MFMA-phase, so LDS time and MFMA time
// ADDED (~2760 cy measured). Now:
//  (1) B comes straight global->reg again (Bf is 1 MB, L2-resident), parity
//      rotation Be/Bo with loads issued after the MFMA cluster -> ~1.7-iter
//      flight. LDS/iter drops to 64 KB reads + 16 KB writes (~1000 cy floor).
//  (2) Within-wave software pipeline: read af_hi(kt) || MFMA(lo half), read
//      af_lo(kt+1) || MFMA(hi half). WAR deps pin the order; ds_reads hide
//      under MFMA issue. All ds_reads precede the iter's new DMA (R5 rule).
// FIFO proof (steady): per iter issue [B(kt+2)x4, A(kt+3)x2]; at the wait the
// queue is [B(kt+1)x4, A(kt+2)x2, B(kt+2)x4, A(kt+3)x2]; vmcnt(6) retires
// exactly B(kt+1) (MFMA'd next iter) and A(kt+2) (lo-read-ahead next iter).

typedef unsigned short u16;
typedef unsigned int u32;
typedef __attribute__((ext_vector_type(8))) short bf16x8;   // 8 x bf16 = 4 VGPRs
typedef __attribute__((ext_vector_type(4))) float f32x4;

#define GP_BYTES 35684352    // 16*66*66*256 * 2

__device__ __forceinline__ u16 f2bf(float f) {   // RNE f32->bf16
  u32 u = __float_as_uint(f);
  u32 r = u + 0x7fffu + ((u >> 16) & 1u);
  return (u16)(r >> 16);
}
__device__ __forceinline__ u32 pack2(float a, float b) {
  return (u32)f2bf(a) | ((u32)f2bf(b) << 16);
}

// ---------------- kernel 1: zero-padded bf16 copy of g ----------------
__global__ __launch_bounds__(256) void pad_convert(const float* __restrict__ g,
                                                   u16* __restrict__ gp) {
  int id = blockIdx.x * 256 + threadIdx.x;      // one thread per 8 channels
  if (id >= 2230272) return;                    // 16*66*66*32
  int c8 = id & 31;
  int t = id >> 5;
  int xx = t % 66;
  int s = t / 66;
  int yy = s % 66;
  int b  = s / 66;
  u32 o0 = 0, o1 = 0, o2 = 0, o3 = 0;
  if (yy != 0 && yy != 65 && xx != 0 && xx != 65) {
    const float* src = g + ((((b << 6) + yy - 1) << 6) + xx - 1) * 256 + (c8 << 3);
    float4 fa = *(const float4*)src;
    float4 fb = *(const float4*)(src + 4);
    o0 = pack2(fa.x, fa.y);
    o1 = pack2(fa.z, fa.w);
    o2 = pack2(fb.x, fb.y);
    o3 = pack2(fb.z, fb.w);
  }
  uint4 v; v.x = o0; v.y = o1; v.z = o2; v.w = o3;
  *(uint4*)(gp + (size_t)id * 8) = v;
}

// ---------------- kernel 2: MFMA weight fold into fragment-ordered Bf ----------------
// Bf u16 index: ((d*8 + c32)*16 + o16)*512 + lane*8 + e, where lane = (o&15) + ((c>>3)&3)*16
// holds M_d[c = c32*32 + (lane>>4)*8 + e][o = o16*16 + (lane&15)]  (B-operand frag order).
__global__ __launch_bounds__(256) void build_mt(const float* __restrict__ Wd,
                                                const float* __restrict__ Wc,
                                                u16* __restrict__ Bf) {
  __shared__ __align__(16) u16 As[128 * 32];
  __shared__ __align__(16) u16 Bs[128 * 32];
  const int bid = blockIdx.x;          // 32 blocks: 2 n-tiles x (8 d x 2 c-halves)
  const int n0    = (bid & 1) << 7;
  const int mblk  = bid >> 1;          // 0..15
  const int d     = mblk >> 1;
  const int chalf = (mblk & 1) << 7;
  const int tid  = threadIdx.x;
  const int lane = tid & 63, wid = tid >> 6;
  const int wm = (wid >> 1) << 6, wn = (wid & 1) << 6;
  const int quad = lane >> 4, r16 = lane & 15;
  const int srow = tid >> 1, hh = tid & 1;
  const int swz  = (srow >> 1) & 3;
  const int ssl  = (quad ^ ((r16 >> 1) & 3)) << 3;
  f32x4 acc[4][4] = {};

  for (int e0 = 0; e0 < 256; e0 += 32) {
    __syncthreads();
    const float* pa = Wd + (size_t)(d * 256 + chalf + srow) * 256 + e0 + hh * 16;
    const float* pb = Wc + (size_t)(n0 + srow) * 2048 + d * 256 + e0 + hh * 16;
#pragma unroll
    for (int i = 0; i < 2; ++i) {
      float4 a0 = *(const float4*)(pa + i * 8);
      float4 a1 = *(const float4*)(pa + i * 8 + 4);
      float4 b0 = *(const float4*)(pb + i * 8);
      float4 b1 = *(const float4*)(pb + i * 8 + 4);
      uint4 va, vb;
      va.x = pack2(a0.x, a0.y); va.y = pack2(a0.z, a0.w);
      va.z = pack2(a1.x, a1.y); va.w = pack2(a1.z, a1.w);
      vb.x = pack2(b0.x, b0.y); vb.y = pack2(b0.z, b0.w);
      vb.z = pack2(b1.x, b1.y); vb.w = pack2(b1.z, b1.w);
      int slot = (2 * hh + i) ^ swz;
      *(uint4*)&As[srow * 32 + slot * 8] = va;
      *(uint4*)&Bs[srow * 32 + slot * 8] = vb;
    }
    __syncthreads();
    bf16x8 bfr[4];
#pragma unroll
    for (int nt = 0; nt < 4; ++nt)
      bfr[nt] = *(const bf16x8*)&Bs[(wn + nt * 16 + r16) * 32 + ssl];
#pragma unroll
    for (int mt = 0; mt < 4; ++mt) {
      bf16x8 af = *(const bf16x8*)&As[(wm + mt * 16 + r16) * 32 + ssl];
#pragma unroll
      for (int nt = 0; nt < 4; ++nt)
        acc[mt][nt] = __builtin_amdgcn_mfma_f32_16x16x32_bf16(af, bfr[nt], acc[mt][nt], 0, 0, 0);
    }
  }
  // scatter into fragment-ordered Bf (C/D layout: col=o=r16-based, row=c=quad*4+reg)
#pragma unroll
  for (int mt = 0; mt < 4; ++mt) {
#pragma unroll
    for (int nt = 0; nt < 4; ++nt) {
      const int o = n0 + wn + nt * 16 + r16;
      f32x4 v = acc[mt][nt];
#pragma unroll
      for (int r = 0; r < 4; ++r) {
        const int c = chalf + wm + mt * 16 + quad * 4 + r;
        const int lane2 = (o & 15) + (((c >> 3) & 3) << 4);
        const size_t idx = ((size_t)((d * 8 + (c >> 5)) * 16 + (o >> 4)) * 512) + lane2 * 8 + (c & 7);
        Bf[idx] = f2bf(v[r]);
      }
    }
  }
}

// ---------------- kernel 3: main implicit-GEMM conv ----------------
// directions (dx,dy) -> source offset (ox,oy)=(-dx,-dy); DOFF = (oy*66+ox)*256 in gp elems
__constant__ int DOFF[8] = {16896, 16640, -256, -17152, -16896, -16640, 256, 17152};

__device__ __forceinline__ void async16(const u16* g, u16* l) {
  __builtin_amdgcn_global_load_lds((const __attribute__((address_space(1))) u32*)g,
                                   (__attribute__((address_space(3))) u32*)l, 16, 0, 0);
}

__global__ __launch_bounds__(512, 2) void conv_gemm(const u16* __restrict__ gp,
                                                    const u16* __restrict__ Bf,
                                                    const float* __restrict__ bc,
                                                    float* __restrict__ out) {
  __shared__ __align__(16) u16 Asm[4][8192];   // 4-stage A only, 64 KB
  const int bid = blockIdx.x;                  // 256 blocks, 1/CU
  const int id2 = ((bid & 7) << 5) | (bid >> 3);  // XCD x -> images 2x, 2x+1
  const int b   = id2 >> 4;                    // image
  const int y0  = (id2 & 15) << 2;             // 4 y-lines per block (BM=256)

  const int tid  = threadIdx.x;                // 0..511
  const int lane = tid & 63;
  const int wid  = tid >> 6;                   // 0..7
  const int wm   = (wid >> 2) << 7;            // 0 / 128   (2 M-warps)
  const int wn   = (wid & 3) << 6;             // 0/64/128/192 (4 N-warps)
  const int quad = lane >> 4;
  const int r16  = lane & 15;

  // A staging: thread t -> LDS slot t*16B (+4096 elems for rows 128..255);
  // source chunk pre-XORed so linear LDS + swizzled ds_read stays conflict-free.
  const int chunk = (tid & 3) ^ ((tid >> 3) & 3);
  const u16* baseA = gp + ((b * 66 + y0 + 1 + (tid >> 8)) * 66 + ((tid >> 2) & 63) + 1) * 256
                        + (chunk << 3);
  const int ldso = tid * 8;

  // B fragment base: this wave covers o16 = (wn>>4)+nt; per kt stride 8192 u16
  const u16* baseBf = Bf + ((wn >> 4) << 9) + lane * 8;

  const int ssl = (quad ^ ((r16 >> 1) & 3)) << 3;

  f32x4 acc[8][4] = {};
  bf16x8 Be[4], Bo[4];        // B parity rotation (even/odd kt)
  bf16x8 afl[4], afh[4];      // A fragment halves (software pipeline)

  auto issueA = [&](int kt) {                  // DMA 16 KB A tile kt into Asm[kt&3]
    const int off = DOFF[kt >> 3] + ((kt & 7) << 5);
    async16(baseA + off,         Asm[kt & 3] + ldso);           // rows 0..127
    async16(baseA + off + 33792, Asm[kt & 3] + 4096 + ldso);    // rows 128..255 (+2 y-lines)
  };
  auto loadB = [&](int kt, bf16x8* dst) {      // 4 coalesced dwordx4 from L2
    const u16* bp = baseBf + (size_t)kt * 8192;
#pragma unroll
    for (int nt = 0; nt < 4; ++nt) dst[nt] = *(const bf16x8*)(bp + nt * 512);
  };
  auto readAh = [&](int kt, bf16x8* af, int h) {   // h=0: mt 0..3, h=1: mt 4..7
    const u16* Ab = Asm[kt & 3];
#pragma unroll
    for (int mt = 0; mt < 4; ++mt)
      af[mt] = *(const bf16x8*)&Ab[(wm + (h * 4 + mt) * 16 + r16) * 32 + ssl];
  };
  auto mfma_half = [&](const bf16x8* af, const bf16x8* bb, int h) {
    __builtin_amdgcn_s_setprio(1);
#pragma unroll
    for (int mt = 0; mt < 4; ++mt)
#pragma unroll
      for (int nt = 0; nt < 4; ++nt)
        acc[h * 4 + mt][nt] =
            __builtin_amdgcn_mfma_f32_16x16x32_bf16(af[mt], bb[nt], acc[h * 4 + mt][nt], 0, 0, 0);
    __builtin_amdgcn_s_setprio(0);
  };

  // body(kt): afl holds lo(kt) (read last iter). Reads hi(kt) || MFMA-lo, reads
  // lo(kt+1) || MFMA-hi (WAR on afl keeps order). Loads AFTER MFMA (WAR on bu).
  auto body = [&](int kt, bf16x8* bu, bool doB, bool doA, int vm) {
    readAh(kt, afh, 1);            // ds_reads first (R5 alias rule)
    mfma_half(afl, bu, 0);
    readAh(kt + 1, afl, 0);        // read-ahead next iter's lo half
    mfma_half(afh, bu, 1);
    if (doB) loadB(kt + 2, bu);    // same-parity buffer, dead after the MFMAs above
    if (doA) issueA(kt + 3);
    if (vm == 6)      asm volatile("s_waitcnt vmcnt(6)" ::: "memory");
    else if (vm == 4) asm volatile("s_waitcnt vmcnt(4)" ::: "memory");
    else              asm volatile("s_waitcnt vmcnt(0)" ::: "memory");
    asm volatile("s_barrier" ::: "memory");
  };

  // prologue: FIFO = [B0x4, A0x2, A1x2, B1x4, A2x2] (14); vmcnt(6) retires B0,A0,A1
  // (A1 must be complete: iter 0 read-aheads lo(1)).
  loadB(0, Be);
  issueA(0);
  issueA(1);
  loadB(1, Bo);
  issueA(2);
  asm volatile("s_waitcnt vmcnt(6)" ::: "memory");
  asm volatile("s_barrier" ::: "memory");
  readAh(0, afl, 0);               // pre-read lo(0)

  for (int kt = 0; kt < 60; kt += 2) {         // explicit parity: no runtime-indexed regs
    body(kt,     Be, true, true, 6);
    body(kt + 1, Bo, true, true, 6);
  }
  body(60, Be, true,  true,  6);   // loads B62->Be, issues A63
  // kt=61: queue [B62x4, A63x2, B63x4]; vmcnt(4) retires B62 + A63 (lo(63) read at kt=62)
  body(61, Bo, true,  false, 4);   // loads B63->Bo
  // kt=62: queue [B63x4]; vmcnt(0) retires it (MFMA'd at kt=63)
  body(62, Be, false, false, 0);
  // kt=63 (no more reads-ahead, no issues, no barrier)
  readAh(63, afh, 1);
  mfma_half(afl, Bo, 0);
  mfma_half(afh, Bo, 1);

  // epilogue: C/D layout col=lane&15, row=quad*4+reg; block rows = b*4096 + y0*64 + r
  const int pbase = (b * 64 + y0) * 64;
#pragma unroll
  for (int nt = 0; nt < 4; ++nt) {
    const int o = wn + nt * 16 + r16;
    const float bias = bc[o];
#pragma unroll
    for (int mt = 0; mt < 8; ++mt) {
      const int pr = pbase + wm + mt * 16 + quad * 4;
      f32x4 v = acc[mt][nt];
#pragma unroll
      for (int r = 0; r < 4; ++r)
        out[(size_t)(pr + r) * 256 + o] = v[r] + bias;
    }
  }
}

extern "C" void kernel_launch(void* const* d_in, const int* in_sizes, int n_in,
                              void* d_out, int out_size, void* d_ws, size_t ws_size,
                              hipStream_t stream) {
  const float* g  = (const float*)d_in[0];   // [16,64,64,256] f32
  const float* Wd = (const float*)d_in[1];   // [8,256,256]
  const float* Wc = (const float*)d_in[2];   // [256,2048]
  const float* bc = (const float*)d_in[3];   // [256]
  float* out = (float*)d_out;                // [16,64,64,256] f32
  u16* gp = (u16*)d_ws;                            // 35.7 MB padded bf16 input
  u16* Bf = (u16*)((char*)d_ws + GP_BYTES);        // 1 MB fragment-ordered weights

  pad_convert<<<8712, 256, 0, stream>>>(g, gp);
  build_mt<<<32, 256, 0, stream>>>(Wd, Wc, Bf);
  conv_gemm<<<256, 512, 0, stream>>>(gp, Bf, bc, out);
}

// Round 5
// 181.871 us; speedup vs baseline: 1.0471x; 1.0471x over previous
//
#include <hip/hip_runtime.h>

// DirectionalProcessor: out[b,y,x,o] = bc[o] + sum_{d,c} g[b,y-dy_d,x-dx_d,c] * M_d[c,o]
// with M_d[c,o] = sum_e Wd[d,c,e]*Wc[o,d*256+e]  (folded -> 68.7 GFLOP implicit GEMM
// [65536 x 2048] @ [2048 x 256], B,H,W,C=16,64,64,256, 8 dirs).
//
// R9 (resubmit after infra failure; full correctness audit in session notes).
// Halo-slab restructure. R6/R7/R8 all sat at 72-80 us (MfmaUtil 36-40%) because
// the loop paid 64 vmcnt+barrier intervals and staged A 8x redundantly: the 8
// direction tiles are SHIFTED VIEWS of one 6x66 halo slab. Now each stage stages
// the 6x66x32ch slab ONCE (25.6 KB, 3-buffer rotation), then runs all 8 directions
// out of it with compile-time spatial base offsets. Barriers 64 -> 8; A-DMA 8x
// down (1 MB -> 205 KB/block). Within a stage: 8 sub-phases of 32 MFMA with the
// R8 half-split read-ahead; B global->reg parity (Be/Bo), 2-subphase flight.
// Swizzle: LDS chunk (s,slot) holds source chunk slot^((s>>1)&3) (pre-swizzled
// global src, linear DMA dest); reads use the same XOR; swizzle is mt-invariant
// (16*mt = 0 mod 4 in (s>>1)&3) and conflict-free for ANY +-1 x/y shift.
// FIFO ledger (per wave, steady stage cb, issue order):
//   prev stage: ... B(cb,0)x4 [d=6], B(cb,1)x4 [d=7], slab(cb+1)x4 [stage end]
//   this stage: B(cb,2..7)x4 [d=0..5], B(cb+1,0)x4 [d=6], B(cb+1,1)x4 [d=7],
//               slab(cb+2)x4, then s_waitcnt vmcnt(12) -> retires slab(cb+1) and
//               everything older, keeps [B(cb+1,0),B(cb+1,1),slab(cb+2)] flying.
//   compiler auto-waits cover B-register uses (vmcnt(8)/(4) at d=0/1). Stage 6:
//   no slab issue, vmcnt(8). Stage 7: no tail B loads, no end barrier.

typedef unsigned short u16;
typedef unsigned int u32;
typedef __attribute__((ext_vector_type(8))) short bf16x8;   // 8 x bf16 = 4 VGPRs
typedef __attribute__((ext_vector_type(4))) float f32x4;

#define GP_BYTES 35684352    // 16*66*66*256 * 2

__device__ __forceinline__ u16 f2bf(float f) {   // RNE f32->bf16
  u32 u = __float_as_uint(f);
  u32 r = u + 0x7fffu + ((u >> 16) & 1u);
  return (u16)(r >> 16);
}
__device__ __forceinline__ u32 pack2(float a, float b) {
  return (u32)f2bf(a) | ((u32)f2bf(b) << 16);
}

// ---------------- kernel 1: zero-padded bf16 copy of g ----------------
__global__ __launch_bounds__(256) void pad_convert(const float* __restrict__ g,
                                                   u16* __restrict__ gp) {
  int id = blockIdx.x * 256 + threadIdx.x;      // one thread per 8 channels
  if (id >= 2230272) return;                    // 16*66*66*32
  int c8 = id & 31;
  int t = id >> 5;
  int xx = t % 66;
  int s = t / 66;
  int yy = s % 66;
  int b  = s / 66;
  u32 o0 = 0, o1 = 0, o2 = 0, o3 = 0;
  if (yy != 0 && yy != 65 && xx != 0 && xx != 65) {
    const float* src = g + ((((b << 6) + yy - 1) << 6) + xx - 1) * 256 + (c8 << 3);
    float4 fa = *(const float4*)src;
    float4 fb = *(const float4*)(src + 4);
    o0 = pack2(fa.x, fa.y);
    o1 = pack2(fa.z, fa.w);
    o2 = pack2(fb.x, fb.y);
    o3 = pack2(fb.z, fb.w);
  }
  uint4 v; v.x = o0; v.y = o1; v.z = o2; v.w = o3;
  *(uint4*)(gp + (size_t)id * 8) = v;
}

// ---------------- kernel 2: MFMA weight fold into fragment-ordered Bf ----------------
// Bf u16 index: ((d*8 + c32)*16 + o16)*512 + lane*8 + e, where lane = (o&15) + ((c>>3)&3)*16
// holds M_d[c = c32*32 + (lane>>4)*8 + e][o = o16*16 + (lane&15)]  (B-operand frag order).
__global__ __launch_bounds__(256) void build_mt(const float* __restrict__ Wd,
                                                const float* __restrict__ Wc,
                                                u16* __restrict__ Bf) {
  __shared__ __align__(16) u16 As[128 * 32];
  __shared__ __align__(16) u16 Bs[128 * 32];
  const int bid = blockIdx.x;          // 32 blocks: 2 n-tiles x (8 d x 2 c-halves)
  const int n0    = (bid & 1) << 7;
  const int mblk  = bid >> 1;          // 0..15
  const int d     = mblk >> 1;
  const int chalf = (mblk & 1) << 7;
  const int tid  = threadIdx.x;
  const int lane = tid & 63, wid = tid >> 6;
  const int wm = (wid >> 1) << 6, wn = (wid & 1) << 6;
  const int quad = lane >> 4, r16 = lane & 15;
  const int srow = tid >> 1, hh = tid & 1;
  const int swz  = (srow >> 1) & 3;
  const int ssl  = (quad ^ ((r16 >> 1) & 3)) << 3;
  f32x4 acc[4][4] = {};

  for (int e0 = 0; e0 < 256; e0 += 32) {
    __syncthreads();
    const float* pa = Wd + (size_t)(d * 256 + chalf + srow) * 256 + e0 + hh * 16;
    const float* pb = Wc + (size_t)(n0 + srow) * 2048 + d * 256 + e0 + hh * 16;
#pragma unroll
    for (int i = 0; i < 2; ++i) {
      float4 a0 = *(const float4*)(pa + i * 8);
      float4 a1 = *(const float4*)(pa + i * 8 + 4);
      float4 b0 = *(const float4*)(pb + i * 8);
      float4 b1 = *(const float4*)(pb + i * 8 + 4);
      uint4 va, vb;
      va.x = pack2(a0.x, a0.y); va.y = pack2(a0.z, a0.w);
      va.z = pack2(a1.x, a1.y); va.w = pack2(a1.z, a1.w);
      vb.x = pack2(b0.x, b0.y); vb.y = pack2(b0.z, b0.w);
      vb.z = pack2(b1.x, b1.y); vb.w = pack2(b1.z, b1.w);
      int slot = (2 * hh + i) ^ swz;
      *(uint4*)&As[srow * 32 + slot * 8] = va;
      *(uint4*)&Bs[srow * 32 + slot * 8] = vb;
    }
    __syncthreads();
    bf16x8 bfr[4];
#pragma unroll
    for (int nt = 0; nt < 4; ++nt)
      bfr[nt] = *(const bf16x8*)&Bs[(wn + nt * 16 + r16) * 32 + ssl];
#pragma unroll
    for (int mt = 0; mt < 4; ++mt) {
      bf16x8 af = *(const bf16x8*)&As[(wm + mt * 16 + r16) * 32 + ssl];
#pragma unroll
      for (int nt = 0; nt < 4; ++nt)
        acc[mt][nt] = __builtin_amdgcn_mfma_f32_16x16x32_bf16(af, bfr[nt], acc[mt][nt], 0, 0, 0);
    }
  }
  // scatter into fragment-ordered Bf (C/D layout: col=o=r16-based, row=c=quad*4+reg)
#pragma unroll
  for (int mt = 0; mt < 4; ++mt) {
#pragma unroll
    for (int nt = 0; nt < 4; ++nt) {
      const int o = n0 + wn + nt * 16 + r16;
      f32x4 v = acc[mt][nt];
#pragma unroll
      for (int r = 0; r < 4; ++r) {
        const int c = chalf + wm + mt * 16 + quad * 4 + r;
        const int lane2 = (o & 15) + (((c >> 3) & 3) << 4);
        const size_t idx = ((size_t)((d * 8 + (c >> 5)) * 16 + (o >> 4)) * 512) + lane2 * 8 + (c & 7);
        Bf[idx] = f2bf(v[r]);
      }
    }
  }
}

// ---------------- kernel 3: main implicit-GEMM conv, halo-slab version ----------------
__device__ __forceinline__ void async16(const u16* g, u16* l) {
  __builtin_amdgcn_global_load_lds((const __attribute__((address_space(1))) u32*)g,
                                   (__attribute__((address_space(3))) u32*)l, 16, 0, 0);
}

__global__ __launch_bounds__(512, 2) void conv_gemm(const u16* __restrict__ gp,
                                                    const u16* __restrict__ Bf,
                                                    const float* __restrict__ bc,
                                                    float* __restrict__ out) {
  // 3 rotating halo slabs: 6x66 spatial x 32 ch, 1600 16B-chunks (16 pad) = 25.6 KB each
  __shared__ __align__(16) u16 slab[3][12800];
  const int bid = blockIdx.x;                  // 256 blocks, 1/CU
  const int id2 = ((bid & 7) << 5) | (bid >> 3);  // XCD x -> images 2x, 2x+1
  const int b   = id2 >> 4;                    // image
  const int y0  = (id2 & 15) << 2;             // 4 output y-lines per block (BM=256)

  const int tid  = threadIdx.x;                // 0..511
  const int lane = tid & 63;
  const int wid  = tid >> 6;                   // 0..7
  const int wm   = (wid >> 2) << 7;            // 0 / 128   (2 M-warps)
  const int wn   = (wid & 3) << 6;             // 0/64/128/192 (4 N-warps)
  const int quad = lane >> 4;
  const int r16  = lane & 15;

  // ---- slab staging precompute: 4 chunks/thread; chunk idx -> s=idx>>2, slot=idx&3;
  // LDS dest linear (idx*16B, wave-uniform base + lane*16); SOURCE chunk pre-swizzled
  // cs = slot ^ ((s>>1)&3). i=3 covers remainder chunks 1536..1583 (+16 pad, lanes
  // 48..63 of every wave redundantly/identically -> benign; pad reads land <=2KB past
  // gp = inside Bf, harmless; pad LDS chunks never read). All waves issue exactly 4
  // DMAs -> vmcnt ledger wave-uniform.
  const int i0 = tid, i1 = tid + 512, i2 = tid + 1024, i3 = 1536 + lane;
  const u16 *p0, *p1, *p2, *p3;
  {
    const size_t rowb = (size_t)(b * 66 + y0) * 66;
    int s, c;
    s = i0 >> 2; c = (i0 & 3) ^ ((s >> 1) & 3);
    p0 = gp + (rowb + (s / 66) * 66 + (s % 66)) * 256 + c * 8;
    s = i1 >> 2; c = (i1 & 3) ^ ((s >> 1) & 3);
    p1 = gp + (rowb + (s / 66) * 66 + (s % 66)) * 256 + c * 8;
    s = i2 >> 2; c = (i2 & 3) ^ ((s >> 1) & 3);
    p2 = gp + (rowb + (s / 66) * 66 + (s % 66)) * 256 + c * 8;
    s = i3 >> 2; c = (i3 & 3) ^ ((s >> 1) & 3);
    p3 = gp + (rowb + (s / 66) * 66 + (s % 66)) * 256 + c * 8;
  }
  const int l0 = i0 * 8, l1 = i1 * 8, l2 = i2 * 8, l3 = i3 * 8;   // elem offsets

  // B fragment base (same layout as R8); per-stage slice stride 8192 elems (kt=d*8+cb)
  const u16* baseBf = Bf + ((wn >> 4) << 9) + lane * 8;

  const int swm = (wm >> 6) * 66 + r16;        // + K(d,half) -> source spatial s
  const int q8  = quad << 3;                   // quad slot in elems

  // K(d,half) = (half + 1 + oyd)*66 + (1 + oxd); dir order matches Bf (d index)
  // dirs (oxd,oyd): d0(0,1) d1(-1,1) d2(-1,0) d3(-1,-1) d4(0,-1) d5(1,-1) d6(1,0) d7(1,1)
  constexpr int KLO[8] = {133, 132, 66,  0,  1,  2,  68, 134};
  constexpr int KHI[8] = {199, 198, 132, 66, 67, 68, 134, 200};
  // B-load elem offset from pB at sub-phase d: d<=5 -> B(cb,d+2); d=6 -> B(cb+1,0); d=7 -> B(cb+1,1)
  constexpr int LBO[8] = {2 * 65536, 3 * 65536, 4 * 65536, 5 * 65536,
                          6 * 65536, 7 * 65536, 8192, 8192 + 65536};

  f32x4 acc[8][4] = {};
  bf16x8 Be[4], Bo[4];        // B parity regs (even/odd sub-phase)
  bf16x8 afl[4], afh[4];      // A fragment halves (software pipeline)

  auto issueSlab = [&](u16* dst, int ch) {     // stage slab for channel-block ch/32
    async16(p0 + ch, dst + l0);
    async16(p1 + ch, dst + l1);
    async16(p2 + ch, dst + l2);
    async16(p3 + ch, dst + l3);
  };
  auto loadB = [&](const u16* pB, int off, bf16x8* dst) {
#pragma unroll
    for (int nt = 0; nt < 4; ++nt) dst[nt] = *(const bf16x8*)(pB + off + nt * 512);
  };
  auto readAh = [&](const u16* bufR, int K, bf16x8* af) {
    const int s  = swm + K;
    const int sw = q8 ^ (((s >> 1) & 3) << 3);
    const u16* p = bufR + s * 32 + sw;
#pragma unroll
    for (int mt = 0; mt < 4; ++mt) af[mt] = *(const bf16x8*)(p + mt * 512);
  };
  auto mfma_half = [&](const bf16x8* af, const bf16x8* bb, int h) {
    __builtin_amdgcn_s_setprio(1);
#pragma unroll
    for (int mt = 0; mt < 4; ++mt)
#pragma unroll
      for (int nt = 0; nt < 4; ++nt)
        acc[h * 4 + mt][nt] =
            __builtin_amdgcn_mfma_f32_16x16x32_bf16(af[mt], bb[nt], acc[h * 4 + mt][nt], 0, 0, 0);
    __builtin_amdgcn_s_setprio(0);
  };

  // 8 sub-phases: half-split read-ahead (R8 pattern); afl(d=0) pre-read by caller.
  // tailLoads=false (stage 7) skips the d=6/7 cross-stage B prefetches.
  auto stage_core = [&](const u16* bufR, const u16* pB, bool tailLoads) {
#pragma unroll
    for (int d = 0; d < 8; ++d) {
      bf16x8* bu = (d & 1) ? Bo : Be;
      readAh(bufR, KHI[d], afh);               // hi(d)
      mfma_half(afl, bu, 0);
      if (d < 7) readAh(bufR, KLO[d + 1], afl); // read-ahead lo(d+1)
      mfma_half(afh, bu, 1);
      if (d < 6 || tailLoads) loadB(pB, LBO[d], bu);   // after mfma: WAR on bu
    }
  };

  // ---- prologue: slab(0), B(0,0), B(0,1), slab(1); vmcnt(12) retires slab(0) only ----
  issueSlab(slab[0], 0);
  loadB(baseBf, 0, Be);            // B(0,0)  (kt=0)
  loadB(baseBf, 65536, Bo);        // B(0,1)  (kt=8)
  issueSlab(slab[1], 32);
  asm volatile("s_waitcnt vmcnt(12)" ::: "memory");
  asm volatile("s_barrier" ::: "memory");
  readAh(slab[0], KLO[0], afl);    // pre-read lo(d=0) of stage 0

  const u16* pB = baseBf;
  u16* bR = slab[0]; u16* bN = slab[1]; u16* bT = slab[2];
#pragma unroll 1
  for (int cb = 0; cb < 6; ++cb) {
    stage_core(bR, pB, true);
    issueSlab(bT, (cb + 2) * 32);              // after ALL this stage's ds_reads
    asm volatile("s_waitcnt vmcnt(12)" ::: "memory");   // retires slab(cb+1)
    asm volatile("s_barrier" ::: "memory");
    readAh(bN, KLO[0], afl);                   // pre-read lo(0) of next stage
    u16* t = bR; bR = bN; bN = bT; bT = t;
    pB += 8192;
  }
  // stage 6: no slab issue; vmcnt(8) retires slab(7), keeps B(7,0),B(7,1) flying
  stage_core(bR, pB, true);
  asm volatile("s_waitcnt vmcnt(8)" ::: "memory");
  asm volatile("s_barrier" ::: "memory");
  readAh(bN, KLO[0], afl);
  pB += 8192;
  // stage 7: no tail prefetch, no end barrier
  stage_core(bN, pB, false);

  // epilogue: C/D layout col=lane&15, row=quad*4+reg; block rows = b*4096 + y0*64 + r
  const int pbase = (b * 64 + y0) * 64;
#pragma unroll
  for (int nt = 0; nt < 4; ++nt) {
    const int o = wn + nt * 16 + r16;
    const float bias = bc[o];
#pragma unroll
    for (int mt = 0; mt < 8; ++mt) {
      const int pr = pbase + wm + mt * 16 + quad * 4;
      f32x4 v = acc[mt][nt];
#pragma unroll
      for (int r = 0; r < 4; ++r)
        out[(size_t)(pr + r) * 256 + o] = v[r] + bias;
    }
  }
}

extern "C" void kernel_launch(void* const* d_in, const int* in_sizes, int n_in,
                              void* d_out, int out_size, void* d_ws, size_t ws_size,
                              hipStream_t stream) {
  const float* g  = (const float*)d_in[0];   // [16,64,64,256] f32
  const float* Wd = (const float*)d_in[1];   // [8,256,256]
  const float* Wc = (const float*)d_in[2];   // [256,2048]
  const float* bc = (const float*)d_in[3];   // [256]
  float* out = (float*)d_out;                // [16,64,64,256] f32
  u16* gp = (u16*)d_ws;                            // 35.7 MB padded bf16 input
  u16* Bf = (u16*)((char*)d_ws + GP_BYTES);        // 1 MB fragment-ordered weights

  pad_convert<<<8712, 256, 0, stream>>>(g, gp);
  build_mt<<<32, 256, 0, stream>>>(Wd, Wc, Bf);
  conv_gemm<<<256, 512, 0, stream>>>(gp, Bf, bc, out);
}